// Round 11
// baseline (45.220 us; speedup 1.0000x reference)
//
#include <hip/hip_runtime.h>
#include <hip/hip_bf16.h>

// KoLeo loss, B=8192, D=256, TOPK=1.
// loss = mean_i( -log( ||x_i - x_{nn(i)}|| + 2*EPS ) ),  x = row-normalize(input)
// nn(i) = argmax_{j!=i} dot(x_i, x_j)  -- selection via INT8 MFMA Gram scan
// (q = round(360*x_hat), i32 dots, packed-index int max); the selected
// distance is recomputed exactly in fp32.
//
// r10 lesson: bf16->i8 halved MFMA/LDS/regs but only gained 4us -> dominant
// residual is dtype-invariant. Prime suspect: 262k device-scope 64b atomicMax
// at kernel end. This round: ATOMIC-FREE merge. argmax stores per-slice
// winners to part[32][8192] (plain coalesced stores); koleo_dist merges the
// 32 candidates per row with a u64 shfl butterfly before the exact distance.

#define NB 8192
#define ND 256
#define QROWB 256         // bytes per row of i8 q
#define EPSF 1e-8f
#define OWN 256           // owned cols per block (64 per wave)
#define CSL 256           // streamed rows per block slice
#define NSL (NB / CSL)    // 32 slices
#define TROWS 64          // streamed rows per LDS tile (16 KB)
#define TB 16384          // tile bytes
#define QSCALE 360.0f

typedef __attribute__((ext_vector_type(4))) int i32x4;
typedef __attribute__((ext_vector_type(16))) int i32x16;
typedef unsigned long long ull;

__device__ __forceinline__ int imax(int a, int b) { return a > b ? a : b; }

__device__ __forceinline__ void gload16(const void* g, void* l) {
    __builtin_amdgcn_global_load_lds(
        (const __attribute__((address_space(1))) unsigned int*)g,
        (__attribute__((address_space(3))) unsigned int*)l,
        16, 0, 0);
}

// ---------------- Phase A: row L2-normalize -> i8 quant + norms ---------------
__global__ __launch_bounds__(256) void koleo_normalize(const float* __restrict__ s,
                                                       unsigned int* __restrict__ q32,
                                                       float* __restrict__ norms) {
    const int w = threadIdx.x >> 6, lane = threadIdx.x & 63;
    const int row = blockIdx.x * 4 + w;
    const float4 v = *(const float4*)(s + row * ND + lane * 4);
    float ss = v.x * v.x + v.y * v.y + v.z * v.z + v.w * v.w;
    #pragma unroll
    for (int m = 32; m; m >>= 1) ss += __shfl_xor(ss, m);
    const float nrm = sqrtf(ss);
    const float qs = QSCALE / (nrm + EPSF);
    const int a0 = __float2int_rn(fmaxf(-127.f, fminf(127.f, v.x * qs)));
    const int a1 = __float2int_rn(fmaxf(-127.f, fminf(127.f, v.y * qs)));
    const int a2 = __float2int_rn(fmaxf(-127.f, fminf(127.f, v.z * qs)));
    const int a3 = __float2int_rn(fmaxf(-127.f, fminf(127.f, v.w * qs)));
    const unsigned pk = (unsigned)(a0 & 255) | ((unsigned)(a1 & 255) << 8) |
                        ((unsigned)(a2 & 255) << 16) | ((unsigned)(a3 & 255) << 24);
    q32[row * (QROWB / 4) + lane] = pk;
    if (lane == 0) norms[row] = nrm;
}

// ---------------- Phase B: swapped-operand i8 MFMA argmax ---------------------
// grid (NB/OWN, NSL) = (32, 32) = 1024 blocks; 4 waves/block; 4 blocks/CU.
// Wave holds 64 owned cols as two B-sets (64 regs); streamed rows through
// double-buffered XOR-swizzled LDS. D layout: col=lane&31, row=(r&3)+8*(r>>2)+4h.
// Per-slice winner -> plain store into part[slice][i] (NO atomics).
__global__ __launch_bounds__(256, 4) void koleo_argmax(const char* __restrict__ q8,
                                                       ull* __restrict__ part) {
    __shared__ __align__(16) char ldsc[2 * TB];   // 2 x 16 KB double buffer
    const int tid = threadIdx.x;
    const int lane = tid & 63;
    const int col = lane & 31;             // A row (streamed) / D col (owned)
    const int h = lane >> 5;               // k-half selector
    const int i0 = blockIdx.x * OWN + (tid >> 6) * 64 + col;  // owned col, set 0
    const int i1 = i0 + 32;                                   // owned col, set 1
    const int sbase = blockIdx.y * CSL;
    const bool hasdiag = (blockIdx.x == blockIdx.y);
    const int iloc0 = i0 - sbase, iloc1 = i1 - sbase;

    // staging offsets: 4 x 16B chunks/thread/tile; LDS dest linear, source
    // pre-swizzled with slot16 ^= row&15 (involution within each 256 B row)
    int soff[4];
    #pragma unroll
    for (int ph = 0; ph < 4; ++ph) {
        const int idx = ph * 256 + tid;
        const int row = idx >> 4, c16 = idx & 15;
        soff[ph] = row * QROWB + ((c16 ^ (row & 15)) << 4);
    }
    const int ldsoff = tid << 4;
    // ds_read: row = s*32+col, slot = (2ks+h) ^ (col&15); buf/s in offset imm
    const int abase = col * QROWB + ((h << 4) ^ ((col & 15) << 4));

    #define KL_STAGE(BUF, TILE) {                                                 \
        const char* gt = q8 + (size_t)(sbase + (TILE) * TROWS) * QROWB;           \
        _Pragma("unroll")                                                         \
        for (int ph = 0; ph < 4; ++ph)                                            \
            gload16(gt + soff[ph], ldsc + (BUF) * TB + ph * 4096 + ldsoff); }

    // stage tile 0 FIRST so the DMA overlaps the bfrag global loads
    KL_STAGE(0, 0)

    // owned-col B fragments: 2 sets x 8 k-steps x 16 i8 (64 regs total)
    i32x4 bfr0[8], bfr1[8];
    {
        const char* bp0 = q8 + (size_t)i0 * QROWB + h * 16;
        const char* bp1 = q8 + (size_t)i1 * QROWB + h * 16;
        #pragma unroll
        for (int ks = 0; ks < 8; ++ks) {
            bfr0[ks] = *(const i32x4*)(bp0 + ks * 32);
            bfr1[ks] = *(const i32x4*)(bp1 + ks * 32);
        }
    }

    int bd0 = (int)0x80000000, bd1 = (int)0x80000000;

    // packed key = dot*256 + lr  (|dot| <= 4.2e6, |key| < 2^31; lr < 256)
    #define KL_COMP(BUF, TILE) {                                                  \
        _Pragma("unroll")                                                         \
        for (int s = 0; s < 2; ++s) {                                             \
            i32x16 a0, a1;                                                        \
            _Pragma("unroll")                                                     \
            for (int z = 0; z < 16; ++z) { a0[z] = 0; a1[z] = 0; }                \
            _Pragma("unroll")                                                     \
            for (int ks = 0; ks < 8; ++ks) {                                      \
                const i32x4 av = *(const i32x4*)(ldsc + (BUF) * TB + s * 8192 +   \
                                                 (abase ^ (ks << 5)));            \
                a0 = __builtin_amdgcn_mfma_i32_32x32x32_i8(av, bfr0[ks], a0, 0, 0, 0); \
                a1 = __builtin_amdgcn_mfma_i32_32x32x32_i8(av, bfr1[ks], a1, 0, 0, 0); \
            }                                                                     \
            const int vb = ((TILE) * 64) | (s * 32) | (h << 2);                   \
            if (hasdiag) {                                                        \
                _Pragma("unroll")                                                 \
                for (int r = 0; r < 16; ++r) {                                    \
                    const int lr = vb | ((r & 3) + 8 * (r >> 2));                 \
                    int k0 = a0[r] * 256 + lr;                                    \
                    int k1 = a1[r] * 256 + lr;                                    \
                    if (lr == iloc0) k0 = (int)0x80000000;                        \
                    if (lr == iloc1) k1 = (int)0x80000000;                        \
                    bd0 = imax(bd0, k0); bd1 = imax(bd1, k1);                     \
                }                                                                 \
            } else {                                                              \
                _Pragma("unroll")                                                 \
                for (int r = 0; r < 16; r += 2) {                                 \
                    const int lrA = vb | ((r & 3) + 8 * (r >> 2));                \
                    const int lrB = vb | (((r + 1) & 3) + 8 * ((r + 1) >> 2));    \
                    bd0 = imax(imax(a0[r] * 256 + lrA, a0[r + 1] * 256 + lrB), bd0); \
                    bd1 = imax(imax(a1[r] * 256 + lrA, a1[r + 1] * 256 + lrB), bd1); \
                }                                                                 \
            }                                                                     \
        } }

    // 4 tiles, classic 2-phase double buffer (stage issued at phase top)
    __syncthreads();
    KL_STAGE(1, 1) KL_COMP(0, 0)
    __syncthreads();
    KL_STAGE(0, 2) KL_COMP(1, 1)
    __syncthreads();
    KL_STAGE(1, 3) KL_COMP(0, 2)
    __syncthreads();
    KL_COMP(1, 3)

    // merge the two k-halves (disjoint row sets), then plain-store the
    // per-slice winner (order-preserving u32 key in the high word)
    {
        const int o0 = __shfl_xor(bd0, 32); bd0 = imax(bd0, o0);
        const int o1 = __shfl_xor(bd1, 32); bd1 = imax(bd1, o1);
        if (lane < 32) {
            const unsigned uk0 = (unsigned)bd0 ^ 0x80000000u;
            const unsigned uk1 = (unsigned)bd1 ^ 0x80000000u;
            const unsigned j0 = (unsigned)(sbase + (bd0 & 255));
            const unsigned j1 = (unsigned)(sbase + (bd1 & 255));
            ull* prow = part + (size_t)blockIdx.y * NB;
            prow[i0] = ((ull)uk0 << 32) | j0;
            prow[i1] = ((ull)uk1 << 32) | j1;
        }
    }
}

// ---------------- Phase C: merge slices + exact fp32 distances ----------------
// grid NB/16 = 512 blocks; 4 waves/block; each wave handles 4 rows.
__global__ __launch_bounds__(256) void koleo_dist(const float* __restrict__ s,
                                                  const float* __restrict__ norms,
                                                  const ull* __restrict__ part,
                                                  float* __restrict__ partial) {
    __shared__ float wsums[4];
    const int w = threadIdx.x >> 6, lane = threadIdx.x & 63;
    float acc = 0.f;
    #pragma unroll
    for (int t = 0; t < 4; ++t) {
        const int i = blockIdx.x * 16 + w * 4 + t;
        // merge the 32 per-slice winners for row i (u64 butterfly max)
        ull k = part[(size_t)(lane & 31) * NB + i];
        #pragma unroll
        for (int m = 1; m < 32; m <<= 1) {
            const ull o = __shfl_xor(k, m);
            if (o > k) k = o;
        }
        const int j = (int)(k & 0xFFFFFFFFull);
        const float sci = 1.0f / (norms[i] + EPSF);
        const float scj = 1.0f / (norms[j] + EPSF);
        const float4 vi = *(const float4*)(s + i * ND + lane * 4);
        const float4 vj = *(const float4*)(s + j * ND + lane * 4);
        const float dx = vi.x * sci - vj.x * scj;
        const float dy = vi.y * sci - vj.y * scj;
        const float dz = vi.z * sci - vj.z * scj;
        const float dw = vi.w * sci - vj.w * scj;
        float d2 = dx * dx + dy * dy + dz * dz + dw * dw;
        #pragma unroll
        for (int mask = 32; mask; mask >>= 1) d2 += __shfl_xor(d2, mask);
        acc += -logf(sqrtf(d2) + EPSF + EPSF);
    }
    if (lane == 0) wsums[w] = acc;
    __syncthreads();
    if (threadIdx.x == 0) partial[blockIdx.x] = wsums[0] + wsums[1] + wsums[2] + wsums[3];
}

// ---------------- Phase D: final reduce (512 partials) ------------------------
__global__ __launch_bounds__(512) void koleo_final(const float* __restrict__ partial,
                                                   float* __restrict__ out) {
    __shared__ float w8[8];
    float v = partial[threadIdx.x];
    #pragma unroll
    for (int mask = 32; mask; mask >>= 1) v += __shfl_xor(v, mask);
    if ((threadIdx.x & 63) == 0) w8[threadIdx.x >> 6] = v;
    __syncthreads();
    if (threadIdx.x == 0) {
        float t = 0.f;
        #pragma unroll
        for (int k = 0; k < 8; ++k) t += w8[k];
        out[0] = t / (float)NB;
    }
}

extern "C" void kernel_launch(void* const* d_in, const int* in_sizes, int n_in,
                              void* d_out, int out_size, void* d_ws, size_t ws_size,
                              hipStream_t stream) {
    const float* s = (const float*)d_in[0];
    float* out = (float*)d_out;
    char* ws = (char*)d_ws;

    // ws layout
    char* q8 = ws;                                                          // 2 MiB i8 q
    float* norms = (float*)(ws + 2 * 1024 * 1024);                          // 32 KiB
    ull* part = (ull*)(ws + 2 * 1024 * 1024 + 32 * 1024);                   // 2 MiB (32 x 8192 u64)
    float* partial = (float*)(ws + 4 * 1024 * 1024 + 64 * 1024);            // 2 KiB

    koleo_normalize<<<NB / 4, 256, 0, stream>>>(s, (unsigned int*)q8, norms);
    koleo_argmax<<<dim3(NB / OWN, NSL), 256, 0, stream>>>(q8, part);
    koleo_dist<<<NB / 16, 256, 0, stream>>>(s, norms, part, partial);
    koleo_final<<<1, 512, 0, stream>>>(partial, out);
}

// Round 12
// 36.224 us; speedup vs baseline: 1.2484x; 1.2484x over previous
//
#include <hip/hip_runtime.h>
#include <hip/hip_bf16.h>

// KoLeo loss, B=8192, D=256, TOPK=1.
// loss = mean_i( -log( ||x_i - x_{nn(i)}|| + 2*EPS ) ),  x = row-normalize(input)
// nn(i) = argmax_{j!=i} dot(x_i, x_j)  -- selection via INT8 MFMA Gram scan
// (q = round(360*x_hat), i32 dots, packed-index int max); selected distance
// recomputed exactly in fp32. Atomic-free merge via part[32][8192] (r11).
//
// r11 lesson: dtype-invariant ~24us residual == sub-full residency (regs>128
// -> 3 waves/SIMD + ragged 2nd round). This round: hard diet to <=128 unified:
//   - packed key constant is compile-time uniform (SGPR): lshl_add + max3,
//     ~1.25 VALU/value; lane-dep hq bit OR'd once into bd before the merge.
//   - soff[4] -> soff0 + ph*4096 (exact swizzle identity).

#define NB 8192
#define ND 256
#define QROWB 256         // bytes per row of i8 q
#define EPSF 1e-8f
#define OWN 256           // owned cols per block (64 per wave)
#define CSL 256           // streamed rows per block slice
#define NSL (NB / CSL)    // 32 slices
#define TROWS 64          // streamed rows per LDS tile (16 KB)
#define TB 16384          // tile bytes
#define QSCALE 360.0f

typedef __attribute__((ext_vector_type(4))) int i32x4;
typedef __attribute__((ext_vector_type(16))) int i32x16;
typedef unsigned long long ull;

__device__ __forceinline__ int imax(int a, int b) { return a > b ? a : b; }

__device__ __forceinline__ void gload16(const void* g, void* l) {
    __builtin_amdgcn_global_load_lds(
        (const __attribute__((address_space(1))) unsigned int*)g,
        (__attribute__((address_space(3))) unsigned int*)l,
        16, 0, 0);
}

// ---------------- Phase A: row L2-normalize -> i8 quant + norms ---------------
__global__ __launch_bounds__(256) void koleo_normalize(const float* __restrict__ s,
                                                       unsigned int* __restrict__ q32,
                                                       float* __restrict__ norms) {
    const int w = threadIdx.x >> 6, lane = threadIdx.x & 63;
    const int row = blockIdx.x * 4 + w;
    const float4 v = *(const float4*)(s + row * ND + lane * 4);
    float ss = v.x * v.x + v.y * v.y + v.z * v.z + v.w * v.w;
    #pragma unroll
    for (int m = 32; m; m >>= 1) ss += __shfl_xor(ss, m);
    const float nrm = sqrtf(ss);
    const float qs = QSCALE / (nrm + EPSF);
    const int a0 = __float2int_rn(fmaxf(-127.f, fminf(127.f, v.x * qs)));
    const int a1 = __float2int_rn(fmaxf(-127.f, fminf(127.f, v.y * qs)));
    const int a2 = __float2int_rn(fmaxf(-127.f, fminf(127.f, v.z * qs)));
    const int a3 = __float2int_rn(fmaxf(-127.f, fminf(127.f, v.w * qs)));
    const unsigned pk = (unsigned)(a0 & 255) | ((unsigned)(a1 & 255) << 8) |
                        ((unsigned)(a2 & 255) << 16) | ((unsigned)(a3 & 255) << 24);
    q32[row * (QROWB / 4) + lane] = pk;
    if (lane == 0) norms[row] = nrm;
}

// ---------------- Phase B: swapped-operand i8 MFMA argmax ---------------------
// grid (NB/OWN, NSL) = (32, 32) = 1024 blocks; 4 waves/block; target 4/CU.
// Wave holds 64 owned cols as two B-sets (64 regs); streamed rows through
// double-buffered XOR-swizzled LDS. D layout: col=lane&31, row=(r&3)+8*(r>>2)+4h.
__global__ __launch_bounds__(256, 4) void koleo_argmax(const char* __restrict__ q8,
                                                       ull* __restrict__ part) {
    __shared__ __align__(16) char ldsc[2 * TB];   // 2 x 16 KB double buffer
    const int tid = threadIdx.x;
    const int lane = tid & 63;
    const int col = lane & 31;             // A row (streamed) / D col (owned)
    const int h = lane >> 5;               // k-half selector
    const int hq = h << 2;                 // D-row bit 2 (kept OUT of packed keys)
    const int i0 = blockIdx.x * OWN + (tid >> 6) * 64 + col;  // owned col, set 0
    const int sbase = blockIdx.y * CSL;
    const bool hasdiag = (blockIdx.x == blockIdx.y);
    const int iloc0 = i0 - sbase, iloc1 = iloc0 + 32;

    // staging: 4 x 16B chunks/thread/tile; LDS dest linear, source pre-swizzled
    // with slot16 ^= row&15. soff(ph) = soff0 + ph*4096 (swizzle is ph-invariant).
    const int soff0 = (tid >> 4) * QROWB + (((tid & 15) ^ ((tid >> 4) & 15)) << 4);
    const int ldsoff = tid << 4;
    // ds_read: row = s*32+col, slot = (2ks+h) ^ (col&15); buf/s in offset imm
    const int abase = col * QROWB + ((h << 4) ^ ((col & 15) << 4));

    #define KL_STAGE(BUF, TILE) {                                                 \
        const char* gt = q8 + (size_t)(sbase + (TILE) * TROWS) * QROWB + soff0;   \
        _Pragma("unroll")                                                         \
        for (int ph = 0; ph < 4; ++ph)                                            \
            gload16(gt + ph * 4096, ldsc + (BUF) * TB + ph * 4096 + ldsoff); }

    // stage tile 0 FIRST so the DMA overlaps the bfrag global loads
    KL_STAGE(0, 0)

    // owned-col B fragments: 2 sets x 8 k-steps x 16 i8 (64 regs total)
    i32x4 bfr0[8], bfr1[8];
    {
        const char* bp0 = q8 + (size_t)i0 * QROWB + h * 16;
        #pragma unroll
        for (int ks = 0; ks < 8; ++ks) {
            bfr0[ks] = *(const i32x4*)(bp0 + ks * 32);
            bfr1[ks] = *(const i32x4*)(bp0 + 32 * QROWB + ks * 32);
        }
    }

    int bd0 = (int)0x80000000, bd1 = (int)0x80000000;

    // packed key = dot*256 + c, c = tile*64+s*32+rofs (COMPILE-TIME uniform;
    // bit 2 reserved for hq, OR'd once at the end). |dot|<=4.2e6 -> no overflow.
    #define KL_COMP(BUF, TILE) {                                                  \
        _Pragma("unroll")                                                         \
        for (int s = 0; s < 2; ++s) {                                             \
            i32x16 a0, a1;                                                        \
            _Pragma("unroll")                                                     \
            for (int z = 0; z < 16; ++z) { a0[z] = 0; a1[z] = 0; }                \
            _Pragma("unroll")                                                     \
            for (int ks = 0; ks < 8; ++ks) {                                      \
                const i32x4 av = *(const i32x4*)(ldsc + (BUF) * TB + s * 8192 +   \
                                                 (abase ^ (ks << 5)));            \
                a0 = __builtin_amdgcn_mfma_i32_32x32x32_i8(av, bfr0[ks], a0, 0, 0, 0); \
                a1 = __builtin_amdgcn_mfma_i32_32x32x32_i8(av, bfr1[ks], a1, 0, 0, 0); \
            }                                                                     \
            const int cb = (TILE) * 64 + s * 32;                                  \
            if (hasdiag) {                                                        \
                _Pragma("unroll")                                                 \
                for (int r = 0; r < 16; ++r) {                                    \
                    const int rofs = (r & 3) + 8 * (r >> 2);                      \
                    const int lrf = cb + rofs + hq;                               \
                    int k0 = a0[r] * 256 + (cb + rofs);                           \
                    int k1 = a1[r] * 256 + (cb + rofs);                           \
                    if (lrf == iloc0) k0 = (int)0x80000000;                       \
                    if (lrf == iloc1) k1 = (int)0x80000000;                       \
                    bd0 = imax(bd0, k0); bd1 = imax(bd1, k1);                     \
                }                                                                 \
            } else {                                                              \
                _Pragma("unroll")                                                 \
                for (int r = 0; r < 16; r += 2) {                                 \
                    const int cA = cb + ((r & 3) + 8 * (r >> 2));                 \
                    const int cB = cb + (((r + 1) & 3) + 8 * ((r + 1) >> 2));     \
                    bd0 = imax(imax(a0[r] * 256 + cA, a0[r + 1] * 256 + cB), bd0); \
                    bd1 = imax(imax(a1[r] * 256 + cA, a1[r + 1] * 256 + cB), bd1); \
                }                                                                 \
            }                                                                     \
        } }

    // 4 tiles, classic 2-phase double buffer (stage issued at phase top)
    __syncthreads();
    KL_STAGE(1, 1) KL_COMP(0, 0)
    __syncthreads();
    KL_STAGE(0, 2) KL_COMP(1, 1)
    __syncthreads();
    KL_STAGE(1, 3) KL_COMP(0, 2)
    __syncthreads();
    KL_COMP(1, 3)

    // restore hq bit (bit 2, disjoint from packed c), merge k-halves, store
    bd0 |= hq; bd1 |= hq;
    {
        const int o0 = __shfl_xor(bd0, 32); bd0 = imax(bd0, o0);
        const int o1 = __shfl_xor(bd1, 32); bd1 = imax(bd1, o1);
        if (lane < 32) {
            const unsigned uk0 = (unsigned)bd0 ^ 0x80000000u;
            const unsigned uk1 = (unsigned)bd1 ^ 0x80000000u;
            const unsigned j0 = (unsigned)(sbase + (bd0 & 255));
            const unsigned j1 = (unsigned)(sbase + (bd1 & 255));
            ull* prow = part + (size_t)blockIdx.y * NB;
            prow[i0] = ((ull)uk0 << 32) | j0;
            prow[i0 + 32] = ((ull)uk1 << 32) | j1;
        }
    }
}

// ---------------- Phase C: merge slices + exact fp32 distances ----------------
// grid NB/16 = 512 blocks; 4 waves/block; each wave handles 4 rows.
__global__ __launch_bounds__(256) void koleo_dist(const float* __restrict__ s,
                                                  const float* __restrict__ norms,
                                                  const ull* __restrict__ part,
                                                  float* __restrict__ partial) {
    __shared__ float wsums[4];
    const int w = threadIdx.x >> 6, lane = threadIdx.x & 63;
    float acc = 0.f;
    #pragma unroll
    for (int t = 0; t < 4; ++t) {
        const int i = blockIdx.x * 16 + w * 4 + t;
        // merge the 32 per-slice winners for row i (u64 butterfly max)
        ull k = part[(size_t)(lane & 31) * NB + i];
        #pragma unroll
        for (int m = 1; m < 32; m <<= 1) {
            const ull o = __shfl_xor(k, m);
            if (o > k) k = o;
        }
        const int j = (int)(k & 0xFFFFFFFFull);
        const float sci = 1.0f / (norms[i] + EPSF);
        const float scj = 1.0f / (norms[j] + EPSF);
        const float4 vi = *(const float4*)(s + i * ND + lane * 4);
        const float4 vj = *(const float4*)(s + j * ND + lane * 4);
        const float dx = vi.x * sci - vj.x * scj;
        const float dy = vi.y * sci - vj.y * scj;
        const float dz = vi.z * sci - vj.z * scj;
        const float dw = vi.w * sci - vj.w * scj;
        float d2 = dx * dx + dy * dy + dz * dz + dw * dw;
        #pragma unroll
        for (int mask = 32; mask; mask >>= 1) d2 += __shfl_xor(d2, mask);
        acc += -logf(sqrtf(d2) + EPSF + EPSF);
    }
    if (lane == 0) wsums[w] = acc;
    __syncthreads();
    if (threadIdx.x == 0) partial[blockIdx.x] = wsums[0] + wsums[1] + wsums[2] + wsums[3];
}

// ---------------- Phase D: final reduce (512 partials) ------------------------
__global__ __launch_bounds__(512) void koleo_final(const float* __restrict__ partial,
                                                   float* __restrict__ out) {
    __shared__ float w8[8];
    float v = partial[threadIdx.x];
    #pragma unroll
    for (int mask = 32; mask; mask >>= 1) v += __shfl_xor(v, mask);
    if ((threadIdx.x & 63) == 0) w8[threadIdx.x >> 6] = v;
    __syncthreads();
    if (threadIdx.x == 0) {
        float t = 0.f;
        #pragma unroll
        for (int k = 0; k < 8; ++k) t += w8[k];
        out[0] = t / (float)NB;
    }
}

extern "C" void kernel_launch(void* const* d_in, const int* in_sizes, int n_in,
                              void* d_out, int out_size, void* d_ws, size_t ws_size,
                              hipStream_t stream) {
    const float* s = (const float*)d_in[0];
    float* out = (float*)d_out;
    char* ws = (char*)d_ws;

    // ws layout
    char* q8 = ws;                                                          // 2 MiB i8 q
    float* norms = (float*)(ws + 2 * 1024 * 1024);                          // 32 KiB
    ull* part = (ull*)(ws + 2 * 1024 * 1024 + 32 * 1024);                   // 2 MiB (32 x 8192 u64)
    float* partial = (float*)(ws + 4 * 1024 * 1024 + 64 * 1024);            // 2 KiB

    koleo_normalize<<<NB / 4, 256, 0, stream>>>(s, (unsigned int*)q8, norms);
    koleo_argmax<<<dim3(NB / OWN, NSL), 256, 0, stream>>>(q8, part);
    koleo_dist<<<NB / 16, 256, 0, stream>>>(s, norms, part, partial);
    koleo_final<<<1, 512, 0, stream>>>(partial, out);
}